// Round 2
// baseline (469.774 us; speedup 1.0000x reference)
//
#include <hip/hip_runtime.h>

// Problem constants (fixed by the reference)
#define N_IMG 8
#define C_CLS 19
#define H_DIM 512
#define W_DIM 1024
#define HW (H_DIM * W_DIM)              // 524288 pixels per image
#define HW2 (HW / 2)                    // 262144 float2 groups per channel
#define TOTAL_ELEMS (N_IMG * C_CLS * HW)
#define RATIO 0.2f

#define BT 256
#define BLOCKS_X (HW2 / BT)             // 1024 blocks per image, exact cover

// Pass 1: per-image per-class sum of p^2 (Q) and argmax histogram (Hist).
// Each thread owns ONE float2 per channel (38 payload VGPRs). q is recycled
// into the payload (no q[19] register array). The old 6-deep 64-lane
// butterfly (114 chained LDS-pipe shuffles/thread) is replaced by:
//   2 DPP-fast shuffles (xor 1,2) -> 64 partials/class in 5 KB LDS ->
//   152 threads each sum 8 + 3 shuffles -> one atomic per class.
__global__ __launch_bounds__(BT, 8) void iw_pass1(
    const float* __restrict__ in,   // (N, C, H, W)
    float* __restrict__ Q,          // [N_IMG * C_CLS], pre-zeroed
    int* __restrict__ Hist)         // [N_IMG * C_CLS], pre-zeroed
{
    const int n   = blockIdx.y;
    const int tid = threadIdx.x;
    const int i   = blockIdx.x * BT + tid;       // float2 index in plane
    const float2* base2 = reinterpret_cast<const float2*>(in + (size_t)n * C_CLS * HW);

    // 19 independent 8B/lane loads, all in flight together
    float2 x[C_CLS];
#pragma unroll
    for (int c = 0; c < C_CLS; ++c)
        x[c] = base2[(size_t)c * HW2 + i];

    int am0, am1;
    float inv0, inv1;
    {   // component 0: argmax (first index on ties) + softmax denom; e^2 in place
        float m = x[0].x; int a = 0;
#pragma unroll
        for (int c = 1; c < C_CLS; ++c) { if (x[c].x > m) { m = x[c].x; a = c; } }
        am0 = a;
        float S = 0.0f;
#pragma unroll
        for (int c = 0; c < C_CLS; ++c) { float e = __expf(x[c].x - m); S += e; x[c].x = e * e; }
        inv0 = __builtin_amdgcn_rcpf(S * S);
    }
    {   // component 1
        float m = x[0].y; int a = 0;
#pragma unroll
        for (int c = 1; c < C_CLS; ++c) { if (x[c].y > m) { m = x[c].y; a = c; } }
        am1 = a;
        float S = 0.0f;
#pragma unroll
        for (int c = 0; c < C_CLS; ++c) { float e = __expf(x[c].y - m); S += e; x[c].y = e * e; }
        inv1 = __builtin_amdgcn_rcpf(S * S);
    }

    __shared__ float qs[C_CLS][BT / 4 + 1];   // 19 x 65 floats = 4.9 KB
    __shared__ int   hs[4][C_CLS];

    // per-thread q_c; 2 DPP shuffle steps; every 4th lane parks the partial
#pragma unroll
    for (int c = 0; c < C_CLS; ++c) {
        float v = fmaf(x[c].y, inv1, x[c].x * inv0);
        v += __shfl_xor(v, 1, 64);
        v += __shfl_xor(v, 2, 64);
        if ((tid & 3) == 0) qs[c][tid >> 2] = v;
    }

    // histogram via wave ballot: transient scalar counts, no VGPR accumulators
    const int wave = tid >> 6, lane = tid & 63;
#pragma unroll
    for (int c = 0; c < C_CLS; ++c) {
        int cnt = (int)__popcll(__ballot(am0 == c))
                + (int)__popcll(__ballot(am1 == c));
        if (lane == 0) hs[wave][c] = cnt;
    }
    __syncthreads();

    // 152 threads: class c = t>>3, slot s = t&7 sums 8 entries, then 3 shuffles
    if (tid < 8 * C_CLS) {
        const int c = tid >> 3, s = tid & 7;
        float v = 0.0f;
#pragma unroll
        for (int j = 0; j < 8; ++j) v += qs[c][s * 8 + j];
        v += __shfl_xor(v, 1, 64);
        v += __shfl_xor(v, 2, 64);
        v += __shfl_xor(v, 4, 64);
        if (s == 0) atomicAdd(&Q[n * C_CLS + c], v);
    }
    if (tid < C_CLS) {
        int hv = hs[0][tid] + hs[1][tid] + hs[2][tid] + hs[3][tid];
        atomicAdd(&Hist[n * C_CLS + tid], hv);
    }
}

// Pass 2: weights from histogram, dot with Q, write scalar mean loss.
__global__ __launch_bounds__(64) void iw_pass2(
    const float* __restrict__ Q,
    const int* __restrict__ Hist,
    float* __restrict__ out)
{
    const int t = threadIdx.x;
    float loss = 0.0f;
    if (t < N_IMG) {
        float h[C_CLS];
        float hsum = 0.0f;
#pragma unroll
        for (int c = 0; c < C_CLS; ++c) {
            float v = (float)Hist[t * C_CLS + c];
            v = (v == 0.0f) ? 1.0f : v;                  // hist[hist==0] = 1
            h[c] = v;
            hsum += v;                                   // sum AFTER replacement
        }
#pragma unroll
        for (int c = 0; c < C_CLS; ++c) {
            float w = powf(hsum / h[c], RATIO);
            loss = fmaf(w, Q[t * C_CLS + c], loss);
        }
    }
    // reduce the 8 per-image values (lanes 8..63 contribute 0)
    loss += __shfl_xor(loss, 1, 64);
    loss += __shfl_xor(loss, 2, 64);
    loss += __shfl_xor(loss, 4, 64);
    if (t == 0)
        out[0] = -loss / (float)TOTAL_ELEMS;
}

extern "C" void kernel_launch(void* const* d_in, const int* in_sizes, int n_in,
                              void* d_out, int out_size, void* d_ws, size_t ws_size,
                              hipStream_t stream)
{
    const float* in = (const float*)d_in[0];
    float* out = (float*)d_out;

    // workspace layout: Q (float[152]) then Hist (int[152])
    float* Q  = (float*)d_ws;
    int* Hist = (int*)((char*)d_ws + N_IMG * C_CLS * sizeof(float));

    hipMemsetAsync(d_ws, 0, N_IMG * C_CLS * (sizeof(float) + sizeof(int)), stream);

    dim3 grid(BLOCKS_X, N_IMG);
    iw_pass1<<<grid, BT, 0, stream>>>(in, Q, Hist);
    iw_pass2<<<1, 64, 0, stream>>>(Q, Hist, out);
}